// Round 15
// baseline (114.745 us; speedup 1.0000x reference)
//
#include <hip/hip_runtime.h>
#include <cstdint>
#include <cstddef>

typedef __attribute__((ext_vector_type(8))) short bf16x8;
typedef __attribute__((ext_vector_type(4))) float f32x4;
typedef __attribute__((ext_vector_type(4))) unsigned short ushort4v;
typedef __attribute__((ext_vector_type(2))) unsigned int uint2v;

#define B_SZ   512
#define D1_IN  40
#define T_DIM  1024
#define D1_OUT 120
#define D2_OUT 64
#define OUT0_SZ (B_SZ * D1_OUT * D2_OUT) // 3932160

// per-bn bitmask of nonzero 32-wide k-steps of W (general sparsity skip)
__device__ unsigned int g_wmask[8];

// ---- helpers ----
__device__ __forceinline__ unsigned short f2bf(float f) {   // RNE
    unsigned int u = __float_as_uint(f);
    u += 0x7FFFu + ((u >> 16) & 1u);
    return (unsigned short)(u >> 16);
}
__device__ __forceinline__ void gld16v(const void* g, void* l) {
    __builtin_amdgcn_global_load_lds(
        (const __attribute__((address_space(1))) unsigned int*)g,
        (__attribute__((address_space(3))) unsigned int*)l, 16, 0, 0);
}

// ---- merged small prep: W2 swizzled re-layout (blocks 0..63), wmask (64..71), w1pad (72) ----
__global__ __launch_bounds__(256) void k_prep_small(const float* __restrict__ W1,
                                                    const float* __restrict__ W,
                                                    const float* __restrict__ W2,
                                                    unsigned short* __restrict__ w2g,
                                                    unsigned short* __restrict__ w1p) {
    int blk = blockIdx.x, tid = threadIdx.x;
    if (blk < 64) {
        __shared__ float tile[32][33];
        int c0 = (blk & 1) * 32, r0 = (blk >> 1) * 32;
        int tx = tid & 31, ty = tid >> 5;
        #pragma unroll
        for (int i = 0; i < 4; i++)
            tile[ty + i * 8][tx] = W2[(size_t)(r0 + ty + i * 8) * D2_OUT + c0 + tx];
        __syncthreads();
        #pragma unroll
        for (int i = 0; i < 4; i++) {
            int s = c0 + ty + i * 8;      // 0..63
            int t = r0 + tx;              // 0..1023
            size_t idx = ((size_t)(t >> 6) * 64 + s) * 64
                       + ((((t >> 3) & 7) ^ (s & 7)) << 3) + (t & 7);
            w2g[idx] = f2bf(tile[tx][ty + i * 8]);
        }
    } else if (blk < 72) {
        __shared__ unsigned int sm[256];
        int bn = blk - 64;
        int rbase = tid >> 5, c0 = (tid & 31) * 4;
        unsigned int m = 0;
        for (int ks = 0; ks < 32; ks++) {
            bool nz = false;
            #pragma unroll
            for (int i = 0; i < 4; i++) {
                int r = ks * 32 + rbase + i * 8;
                float4 v = *(const float4*)(W + (size_t)r * T_DIM + bn * 128 + c0);
                nz |= (v.x != 0.f) | (v.y != 0.f) | (v.z != 0.f) | (v.w != 0.f);
            }
            if (nz) m |= (1u << ks);
        }
        sm[tid] = m;
        __syncthreads();
        if (tid == 0) {
            unsigned int acc = 0;
            for (int i = 0; i < 256; i++) acc |= sm[i];
            g_wmask[bn] = acc;
        }
    } else {
        for (int i = tid; i < 128 * 64; i += 256) {
            int o = i >> 6, f = i & 63;
            w1p[i] = (o < D1_OUT && f < D1_IN) ? f2bf(W1[o * D1_IN + f]) : (unsigned short)0;
        }
    }
}

// ---- wfrag: W (1024x1024 fp32) -> MFMA-A-fragment-ordered bf16 ----
__global__ __launch_bounds__(256) void k_wfrag(const float* __restrict__ W,
                                               unsigned short* __restrict__ wfrag) {
    __shared__ float tl[32 * 132];
    int bn = blockIdx.x >> 5, ks = blockIdx.x & 31;
    int tid = threadIdx.x;
    int k0 = ks * 32, c0 = bn * 128;
    for (int i = tid; i < 1024; i += 256) {
        int r = i >> 5, c4 = i & 31;
        float4 v = *(const float4*)(W + (size_t)(k0 + r) * T_DIM + c0 + c4 * 4);
        *(float4*)&tl[r * 132 + c4 * 4] = v;
    }
    __syncthreads();
    int l = tid & 63, v = tid >> 6;      // 4 waves
    int rr = l & 15, q = l >> 4;
    #pragma unroll
    for (int nn = 0; nn < 2; nn++) {
        int n = v + nn * 4;
        bf16x8 o;
        #pragma unroll
        for (int j = 0; j < 8; j++)
            o[j] = (short)f2bf(tl[(q * 8 + j) * 132 + n * 16 + rr]);
        *(bf16x8*)(wfrag + (((size_t)(bn * 32 + ks) * 8 + n) * 512) + (size_t)l * 8) = o;
    }
}

// ---- GEMM1 + softmax fused (v5): A = softmax(x @ W, axis=1).
//      x staged fp32 via async gld16v (no reg round-trip); frag converts on the fly.
//      A written via LDS transpose -> fully coalesced 512B-segment stores. ----
__global__ __launch_bounds__(512) void k_gemm1sm(const float* __restrict__ x,
                                                 const unsigned short* __restrict__ wfrag,
                                                 float* __restrict__ A) {
    __shared__ float xsf[16 * 1036];            // [row][1024 + 12 pad] fp32 = 66.3KB
    __shared__ float red[16][9];
    int row0 = blockIdx.x * 16;
    int tid = threadIdx.x, l = tid & 63, w = tid >> 6;
    int rr = l & 15, q = l >> 4;
    unsigned int mask = g_wmask[w];
    f32x4 acc[8] = {};

    // async stage: wave w covers chunks w*8..w*8+7 (each 1KB contiguous)
    #pragma unroll
    for (int i = 0; i < 8; i++) {
        int ch = w * 8 + i;                      // 0..63
        int r = ch >> 2, c = ch & 3;             // row, 256-float chunk
        gld16v(x + (size_t)(row0 + r) * T_DIM + c * 256 + l * 4,
               &xsf[r * 1036 + c * 256]);
    }
    __syncthreads();

    // barrier-free K loop; x-fragment converted fp32->bf16 at build (1 frag/ks)
    for (int ks = 0; ks < 32; ks++) {
        if (!((mask >> ks) & 1u)) continue;
        const float* xp = &xsf[rr * 1036 + ks * 32 + q * 8];
        f32x4 xa = *(const f32x4*)xp;
        f32x4 xb2 = *(const f32x4*)(xp + 4);
        bf16x8 bx;
        ((unsigned int*)&bx)[0] = (__float_as_uint(xa.x) >> 16) | (__float_as_uint(xa.y) & 0xFFFF0000u);
        ((unsigned int*)&bx)[1] = (__float_as_uint(xa.z) >> 16) | (__float_as_uint(xa.w) & 0xFFFF0000u);
        ((unsigned int*)&bx)[2] = (__float_as_uint(xb2.x) >> 16) | (__float_as_uint(xb2.y) & 0xFFFF0000u);
        ((unsigned int*)&bx)[3] = (__float_as_uint(xb2.z) >> 16) | (__float_as_uint(xb2.w) & 0xFFFF0000u);
        const unsigned short* wp = wfrag + ((size_t)(w * 32 + ks) * 8) * 512 + (size_t)l * 8;
        #pragma unroll
        for (int n = 0; n < 8; n++) {
            bf16x8 af = *(const bf16x8*)(wp + (size_t)n * 512);
            acc[n] = __builtin_amdgcn_mfma_f32_16x16x32_bf16(af, bx, acc[n], 0, 0, 0);
        }
    }

    // ---- softmax: lane (rr,q) holds E[row0+rr][w*128 + n*16 + q*4 + jj] ----
    float mx = -3.4e38f;
    #pragma unroll
    for (int n = 0; n < 8; n++)
        #pragma unroll
        for (int jj = 0; jj < 4; jj++) mx = fmaxf(mx, acc[n][jj]);
    mx = fmaxf(mx, __shfl_xor(mx, 16));
    mx = fmaxf(mx, __shfl_xor(mx, 32));
    if (l < 16) red[rr][w] = mx;
    __syncthreads();                     // also: all K-loop xsf reads complete
    float g = red[rr][0];
    #pragma unroll
    for (int ww = 1; ww < 8; ww++) g = fmaxf(g, red[rr][ww]);
    __syncthreads();
    float s = 0.f;
    #pragma unroll
    for (int n = 0; n < 8; n++)
        #pragma unroll
        for (int jj = 0; jj < 4; jj++) {
            float p = __expf(acc[n][jj] - g);
            acc[n][jj] = p;
            s += p;
        }
    s += __shfl_xor(s, 16);
    s += __shfl_xor(s, 32);
    if (l < 16) red[rr][w] = s;
    __syncthreads();
    float tot = 0.f;
    #pragma unroll
    for (int ww = 0; ww < 8; ww++) tot += red[rr][ww];
    float inv = 1.f / tot;
    // transpose-stage normalized A-tile into xsf (reuse; all x reads are done)
    #pragma unroll
    for (int n = 0; n < 8; n++) {
        f32x4 o;
        o.x = acc[n][0] * inv; o.y = acc[n][1] * inv;
        o.z = acc[n][2] * inv; o.w = acc[n][3] * inv;
        *(f32x4*)&xsf[rr * 1036 + w * 128 + n * 16 + q * 4] = o;
    }
    __syncthreads();
    // coalesced store: each instr = 2 rows x 512B contiguous segments
    {
        int r2 = tid >> 5, cc = tid & 31;
        float* arow = A + (size_t)(row0 + r2) * T_DIM;
        const float* srow = &xsf[r2 * 1036];
        #pragma unroll
        for (int it = 0; it < 8; it++)
            *(f32x4*)(arow + cc * 4 + it * 128) = *(const f32x4*)(srow + cc * 4 + it * 128);
    }
}

// ---- fused: stage x fp32 + gate (A fp32, L3-hot) via gld16v into group-padded LDS;
//      CONVERT x to bf16 [t][f]; MFMA1, fp32 gate, GEMM2, bias+relu. ----
__global__ __launch_bounds__(512) void k_fused(const float* __restrict__ x,
                                               const float* __restrict__ A,
                                               const unsigned short* __restrict__ w1p,
                                               const unsigned short* __restrict__ w2g,
                                               const float* __restrict__ Bias,
                                               const float* __restrict__ lamp,
                                               float* __restrict__ out) {
    __shared__ float xfst[2][10 * 260];           // x chunk fp32, group-padded  20800B
    __shared__ float gst[2][10 * 260];            // A chunk fp32, group-padded  20800B
    __shared__ unsigned short w2s[64 * 64];       // swizzled w2 chunk (single)   8192B
    __shared__ unsigned short xbt[64 * 72];       // x transposed bf16 [t][f]     9216B
    __shared__ unsigned short xtl[128 * 72];      // X_tilde [o][t]              18432B
    int b = blockIdx.x;
    int tid = threadIdx.x, l = tid & 63, w = tid >> 6;   // 8 waves
    int rr = l & 15, q = l >> 4;
    float lam = fminf(fmaxf(lamp[0], 0.f), 1.f), oml = 1.f - lam;
    bf16x8 aw[2];
    #pragma unroll
    for (int ks = 0; ks < 2; ks++)
        aw[ks] = *(const bf16x8*)(w1p + (w * 16 + rr) * 64 + ks * 32 + q * 8);
    int og = w * 16 + rr;              // lane's fixed o (strip row)
    int am = og % D1_IN;               // gate row
    int amg = (am >> 2) * 260 + (am & 3) * 64;    // group-padded base of gate row
    f32x4 acc2[4] = {};
    const float* xb = x + (size_t)b * D1_IN * T_DIM;
    const float* Ab = A + (size_t)b * D1_IN * T_DIM;

    auto STAGE_XG = [&](int buf, int tc) {
        int t0 = tc * 64;
        int f = w * 4 + (l >> 4);                 // group w: rows 4w..4w+3
        gld16v(xb + (size_t)f * T_DIM + t0 + (l & 15) * 4, &xfst[buf][w * 260]);
        gld16v(Ab + (size_t)f * T_DIM + t0 + (l & 15) * 4, &gst[buf][w * 260]);
        if (w < 2) {
            int f2 = 32 + w * 4 + (l >> 4);       // groups 8,9: rows 32..39
            gld16v(xb + (size_t)f2 * T_DIM + t0 + (l & 15) * 4, &xfst[buf][(8 + w) * 260]);
            gld16v(Ab + (size_t)f2 * T_DIM + t0 + (l & 15) * 4, &gst[buf][(8 + w) * 260]);
        }
    };
    auto STAGE_W2 = [&](int tc) {
        gld16v(w2g + (size_t)tc * 4096 + w * 512 + l * 8, &w2s[w * 512]);
    };
    // transpose-convert xfst[buf] fp32 [f][t] -> xbt bf16 [t][f]; 320 threads
    auto CONVERT = [&](int buf) {
        if (tid < 320) {
            int g = tid >> 5, tp = tid & 31;      // g = f-quad 0..9, tp = t-pair
            const float* src = &xfst[buf][g * 260 + 2 * tp];
            float a0 = src[0],   b0 = src[1];
            float a1 = src[64],  b1 = src[65];
            float a2 = src[128], b2 = src[129];
            float a3 = src[192], b3 = src[193];
            uint2v lo, hi;
            lo.x = (unsigned int)f2bf(a0) | ((unsigned int)f2bf(a1) << 16);
            lo.y = (unsigned int)f2bf(a2) | ((unsigned int)f2bf(a3) << 16);
            hi.x = (unsigned int)f2bf(b0) | ((unsigned int)f2bf(b1) << 16);
            hi.y = (unsigned int)f2bf(b2) | ((unsigned int)f2bf(b3) << 16);
            int t = 2 * tp;
            *(uint2v*)&xbt[t * 72 + g * 4] = lo;
            *(uint2v*)&xbt[(t + 1) * 72 + g * 4] = hi;
        }
    };

    // zero the f>=40 region of xbt once (stays zero; W1 pad rows are zero too)
    {
        int t = tid >> 3, k = tid & 7;
        *(uint2v*)&xbt[t * 72 + 40 + k * 4] = (uint2v){0u, 0u};   // covers f 40..71
    }
    STAGE_XG(0, 0);
    __syncthreads();
    for (int tc = 0; tc < 16; tc++) {
        int cur = tc & 1;
        CONVERT(cur);
        STAGE_W2(tc);
        __syncthreads();                       // A: xbt + w2s ready (vmcnt drained)
        if (tc < 15) STAGE_XG(cur ^ 1, tc + 1);  // prefetch overlaps compute
        // X_bar^T via MFMA: D[t][o], lane holds t = ni*16 + q*4+j at fixed o = og
        f32x4 acc1[4] = {};
        #pragma unroll
        for (int ni = 0; ni < 4; ni++)
            #pragma unroll
            for (int ks = 0; ks < 2; ks++) {
                bf16x8 bx = *(const bf16x8*)&xbt[(ni * 16 + rr) * 72 + ks * 32 + q * 8];
                acc1[ni] = __builtin_amdgcn_mfma_f32_16x16x32_bf16(bx, aw[ks], acc1[ni], 0, 0, 0);
            }
        // gate (fp32 LDS, lane-fixed row am) + pack -> one ds_write_b64 per ni
        const float* gr = &gst[cur][amg];
        #pragma unroll
        for (int ni = 0; ni < 4; ni++) {
            f32x4 gv = *(const f32x4*)(gr + ni * 16 + q * 4);
            float e0 = acc1[ni][0] * (lam * gv.x + oml);
            float e1 = acc1[ni][1] * (lam * gv.y + oml);
            float e2 = acc1[ni][2] * (lam * gv.z + oml);
            float e3 = acc1[ni][3] * (lam * gv.w + oml);
            uint2 pk;
            pk.x = (unsigned int)f2bf(e0) | ((unsigned int)f2bf(e1) << 16);
            pk.y = (unsigned int)f2bf(e2) | ((unsigned int)f2bf(e3) << 16);
            *(uint2*)&xtl[og * 72 + ni * 16 + q * 4] = pk;
        }
        // GEMM2: a2 row = og (same-wave RAW on xtl), b2 from swizzled w2s LDS
        #pragma unroll
        for (int ks2 = 0; ks2 < 2; ks2++) {
            bf16x8 a2 = *(const bf16x8*)&xtl[og * 72 + ks2 * 32 + q * 8];
            #pragma unroll
            for (int ni = 0; ni < 4; ni++) {
                int s = ni * 16 + rr;
                bf16x8 b2 = *(const bf16x8*)&w2s[s * 64 + (((ks2 * 4 + q) ^ (s & 7)) << 3)];
                acc2[ni] = __builtin_amdgcn_mfma_f32_16x16x32_bf16(a2, b2, acc2[ni], 0, 0, 0);
            }
        }
        __syncthreads();                       // B: drains prefetch; protects buffers
    }
    #pragma unroll
    for (int ni = 0; ni < 4; ni++)
        #pragma unroll
        for (int j = 0; j < 4; j++) {
            int row = w * 16 + q * 4 + j;
            if (row < D1_OUT) {
                int col = ni * 16 + rr;
                float v = acc2[ni][j] + Bias[row * D2_OUT + col];
                out[((size_t)b * D1_OUT + row) * D2_OUT + col] = fmaxf(v, 0.f);
            }
        }
}

extern "C" void kernel_launch(void* const* d_in, const int* in_sizes, int n_in,
                              void* d_out, int out_size, void* d_ws, size_t ws_size,
                              hipStream_t stream) {
    const float* x    = (const float*)d_in[0];
    const float* W1   = (const float*)d_in[1];
    const float* W    = (const float*)d_in[2];
    const float* W2   = (const float*)d_in[3];
    const float* Bias = (const float*)d_in[4];
    const float* lam  = (const float*)d_in[5];
    float* out = (float*)d_out;
    float* A   = out + OUT0_SZ;                    // second output region

    char* ws = (char*)d_ws;
    unsigned short* wfrag = (unsigned short*)(ws);              // 2 MB
    unsigned short* w2g   = (unsigned short*)(ws + 2097152);    // 128 KB
    unsigned short* w1p   = (unsigned short*)(ws + 2228224);    // 16 KB (total ~2.25 MB)

    hipLaunchKernelGGL(k_prep_small, dim3(73), dim3(256), 0, stream, W1, W, W2, w2g, w1p);
    hipLaunchKernelGGL(k_wfrag, dim3(256), dim3(256), 0, stream, W, wfrag);
    hipLaunchKernelGGL(k_gemm1sm, dim3(1280), dim3(512), 0, stream, x, wfrag, A);
    hipLaunchKernelGGL(k_fused, dim3(512), dim3(512), 0, stream, x, A, w1p, w2g, Bias, lam, out);
}

// Round 16
// 107.373 us; speedup vs baseline: 1.0687x; 1.0687x over previous
//
#include <hip/hip_runtime.h>
#include <cstdint>
#include <cstddef>

typedef __attribute__((ext_vector_type(8))) short bf16x8;
typedef __attribute__((ext_vector_type(4))) float f32x4;
typedef __attribute__((ext_vector_type(4))) unsigned short ushort4v;
typedef __attribute__((ext_vector_type(2))) unsigned int uint2v;

#define B_SZ   512
#define D1_IN  40
#define T_DIM  1024
#define D1_OUT 120
#define D2_OUT 64
#define OUT0_SZ (B_SZ * D1_OUT * D2_OUT) // 3932160

// per-bn bitmask of nonzero 32-wide k-steps of W (general sparsity skip)
__device__ unsigned int g_wmask[8];

// ---- helpers ----
__device__ __forceinline__ unsigned short f2bf(float f) {   // RNE
    unsigned int u = __float_as_uint(f);
    u += 0x7FFFu + ((u >> 16) & 1u);
    return (unsigned short)(u >> 16);
}
__device__ __forceinline__ void gld16v(const void* g, void* l) {
    __builtin_amdgcn_global_load_lds(
        (const __attribute__((address_space(1))) unsigned int*)g,
        (__attribute__((address_space(3))) unsigned int*)l, 16, 0, 0);
}

// ---- merged small prep: W2 swizzled re-layout (blocks 0..63), wmask (64..71), w1pad (72) ----
__global__ __launch_bounds__(256) void k_prep_small(const float* __restrict__ W1,
                                                    const float* __restrict__ W,
                                                    const float* __restrict__ W2,
                                                    unsigned short* __restrict__ w2g,
                                                    unsigned short* __restrict__ w1p) {
    int blk = blockIdx.x, tid = threadIdx.x;
    if (blk < 64) {
        __shared__ float tile[32][33];
        int c0 = (blk & 1) * 32, r0 = (blk >> 1) * 32;
        int tx = tid & 31, ty = tid >> 5;
        #pragma unroll
        for (int i = 0; i < 4; i++)
            tile[ty + i * 8][tx] = W2[(size_t)(r0 + ty + i * 8) * D2_OUT + c0 + tx];
        __syncthreads();
        #pragma unroll
        for (int i = 0; i < 4; i++) {
            int s = c0 + ty + i * 8;      // 0..63
            int t = r0 + tx;              // 0..1023
            size_t idx = ((size_t)(t >> 6) * 64 + s) * 64
                       + ((((t >> 3) & 7) ^ (s & 7)) << 3) + (t & 7);
            w2g[idx] = f2bf(tile[tx][ty + i * 8]);
        }
    } else if (blk < 72) {
        __shared__ unsigned int sm[256];
        int bn = blk - 64;
        int rbase = tid >> 5, c0 = (tid & 31) * 4;
        unsigned int m = 0;
        for (int ks = 0; ks < 32; ks++) {
            bool nz = false;
            #pragma unroll
            for (int i = 0; i < 4; i++) {
                int r = ks * 32 + rbase + i * 8;
                float4 v = *(const float4*)(W + (size_t)r * T_DIM + bn * 128 + c0);
                nz |= (v.x != 0.f) | (v.y != 0.f) | (v.z != 0.f) | (v.w != 0.f);
            }
            if (nz) m |= (1u << ks);
        }
        sm[tid] = m;
        __syncthreads();
        if (tid == 0) {
            unsigned int acc = 0;
            for (int i = 0; i < 256; i++) acc |= sm[i];
            g_wmask[bn] = acc;
        }
    } else {
        for (int i = tid; i < 128 * 64; i += 256) {
            int o = i >> 6, f = i & 63;
            w1p[i] = (o < D1_OUT && f < D1_IN) ? f2bf(W1[o * D1_IN + f]) : (unsigned short)0;
        }
    }
}

// ---- wfrag: W (1024x1024 fp32) -> MFMA-A-fragment-ordered bf16 ----
__global__ __launch_bounds__(256) void k_wfrag(const float* __restrict__ W,
                                               unsigned short* __restrict__ wfrag) {
    __shared__ float tl[32 * 132];
    int bn = blockIdx.x >> 5, ks = blockIdx.x & 31;
    int tid = threadIdx.x;
    int k0 = ks * 32, c0 = bn * 128;
    for (int i = tid; i < 1024; i += 256) {
        int r = i >> 5, c4 = i & 31;
        float4 v = *(const float4*)(W + (size_t)(k0 + r) * T_DIM + c0 + c4 * 4);
        *(float4*)&tl[r * 132 + c4 * 4] = v;
    }
    __syncthreads();
    int l = tid & 63, v = tid >> 6;      // 4 waves
    int rr = l & 15, q = l >> 4;
    #pragma unroll
    for (int nn = 0; nn < 2; nn++) {
        int n = v + nn * 4;
        bf16x8 o;
        #pragma unroll
        for (int j = 0; j < 8; j++)
            o[j] = (short)f2bf(tl[(q * 8 + j) * 132 + n * 16 + rr]);
        *(bf16x8*)(wfrag + (((size_t)(bn * 32 + ks) * 8 + n) * 512) + (size_t)l * 8) = o;
    }
}

// ---- GEMM1 + softmax fused (v6): A = softmax(x @ W, axis=1).
//      NO x staging: each lane's MFMA fragment is 2 direct float4 global loads
//      (wave footprint = 16 rows x 2 full 64B lines/row, L3-backed) of only the
//      ACTIVE k-slices -> x traffic ~10MB, no stage barrier, ~0 LDS. ----
__global__ __launch_bounds__(512) void k_gemm1sm(const float* __restrict__ x,
                                                 const unsigned short* __restrict__ wfrag,
                                                 float* __restrict__ A) {
    __shared__ float red[16][9];
    int row0 = blockIdx.x * 16;
    int tid = threadIdx.x, l = tid & 63, w = tid >> 6;
    int rr = l & 15, q = l >> 4;
    unsigned int mask = g_wmask[w];
    f32x4 acc[8] = {};
    const float* xrow = x + (size_t)(row0 + rr) * T_DIM;   // lane's fixed row

    // barrier-free K loop: fragment loaded straight from global, converted in-reg
    for (int ks = 0; ks < 32; ks++) {
        if (!((mask >> ks) & 1u)) continue;
        const float* xp = xrow + ks * 32 + q * 8;
        f32x4 xa = *(const f32x4*)xp;
        f32x4 xb2 = *(const f32x4*)(xp + 4);
        bf16x8 bx;
        ((unsigned int*)&bx)[0] = (__float_as_uint(xa.x) >> 16) | (__float_as_uint(xa.y) & 0xFFFF0000u);
        ((unsigned int*)&bx)[1] = (__float_as_uint(xa.z) >> 16) | (__float_as_uint(xa.w) & 0xFFFF0000u);
        ((unsigned int*)&bx)[2] = (__float_as_uint(xb2.x) >> 16) | (__float_as_uint(xb2.y) & 0xFFFF0000u);
        ((unsigned int*)&bx)[3] = (__float_as_uint(xb2.z) >> 16) | (__float_as_uint(xb2.w) & 0xFFFF0000u);
        const unsigned short* wp = wfrag + ((size_t)(w * 32 + ks) * 8) * 512 + (size_t)l * 8;
        #pragma unroll
        for (int n = 0; n < 8; n++) {
            bf16x8 af = *(const bf16x8*)(wp + (size_t)n * 512);
            acc[n] = __builtin_amdgcn_mfma_f32_16x16x32_bf16(af, bx, acc[n], 0, 0, 0);
        }
    }

    // ---- softmax: lane (rr,q) holds E[row0+rr][w*128 + n*16 + q*4 + jj] ----
    float mx = -3.4e38f;
    #pragma unroll
    for (int n = 0; n < 8; n++)
        #pragma unroll
        for (int jj = 0; jj < 4; jj++) mx = fmaxf(mx, acc[n][jj]);
    mx = fmaxf(mx, __shfl_xor(mx, 16));
    mx = fmaxf(mx, __shfl_xor(mx, 32));
    if (l < 16) red[rr][w] = mx;
    __syncthreads();
    float g = red[rr][0];
    #pragma unroll
    for (int ww = 1; ww < 8; ww++) g = fmaxf(g, red[rr][ww]);
    __syncthreads();
    float s = 0.f;
    #pragma unroll
    for (int n = 0; n < 8; n++)
        #pragma unroll
        for (int jj = 0; jj < 4; jj++) {
            float p = __expf(acc[n][jj] - g);
            acc[n][jj] = p;
            s += p;
        }
    s += __shfl_xor(s, 16);
    s += __shfl_xor(s, 32);
    if (l < 16) red[rr][w] = s;
    __syncthreads();
    float tot = 0.f;
    #pragma unroll
    for (int ww = 0; ww < 8; ww++) tot += red[rr][ww];
    float inv = 1.f / tot;
    // store: per (row,n) the 4 q-lanes cover one full 64B line
    size_t rowg = (size_t)(row0 + rr) * T_DIM + w * 128;
    #pragma unroll
    for (int n = 0; n < 8; n++) {
        f32x4 o;
        o.x = acc[n][0] * inv; o.y = acc[n][1] * inv;
        o.z = acc[n][2] * inv; o.w = acc[n][3] * inv;
        *(f32x4*)&A[rowg + n * 16 + q * 4] = o;
    }
}

// ---- fused: stage x fp32 + gate (A fp32, L3-hot) via gld16v into group-padded LDS;
//      CONVERT x to bf16 [t][f]; MFMA1, fp32 gate, GEMM2, bias+relu. ----
__global__ __launch_bounds__(512) void k_fused(const float* __restrict__ x,
                                               const float* __restrict__ A,
                                               const unsigned short* __restrict__ w1p,
                                               const unsigned short* __restrict__ w2g,
                                               const float* __restrict__ Bias,
                                               const float* __restrict__ lamp,
                                               float* __restrict__ out) {
    __shared__ float xfst[2][10 * 260];           // x chunk fp32, group-padded  20800B
    __shared__ float gst[2][10 * 260];            // A chunk fp32, group-padded  20800B
    __shared__ unsigned short w2s[64 * 64];       // swizzled w2 chunk (single)   8192B
    __shared__ unsigned short xbt[64 * 72];       // x transposed bf16 [t][f]     9216B
    __shared__ unsigned short xtl[128 * 72];      // X_tilde [o][t]              18432B
    int b = blockIdx.x;
    int tid = threadIdx.x, l = tid & 63, w = tid >> 6;   // 8 waves
    int rr = l & 15, q = l >> 4;
    float lam = fminf(fmaxf(lamp[0], 0.f), 1.f), oml = 1.f - lam;
    bf16x8 aw[2];
    #pragma unroll
    for (int ks = 0; ks < 2; ks++)
        aw[ks] = *(const bf16x8*)(w1p + (w * 16 + rr) * 64 + ks * 32 + q * 8);
    int og = w * 16 + rr;              // lane's fixed o (strip row)
    int am = og % D1_IN;               // gate row
    int amg = (am >> 2) * 260 + (am & 3) * 64;    // group-padded base of gate row
    f32x4 acc2[4] = {};
    const float* xb = x + (size_t)b * D1_IN * T_DIM;
    const float* Ab = A + (size_t)b * D1_IN * T_DIM;

    auto STAGE_XG = [&](int buf, int tc) {
        int t0 = tc * 64;
        int f = w * 4 + (l >> 4);                 // group w: rows 4w..4w+3
        gld16v(xb + (size_t)f * T_DIM + t0 + (l & 15) * 4, &xfst[buf][w * 260]);
        gld16v(Ab + (size_t)f * T_DIM + t0 + (l & 15) * 4, &gst[buf][w * 260]);
        if (w < 2) {
            int f2 = 32 + w * 4 + (l >> 4);       // groups 8,9: rows 32..39
            gld16v(xb + (size_t)f2 * T_DIM + t0 + (l & 15) * 4, &xfst[buf][(8 + w) * 260]);
            gld16v(Ab + (size_t)f2 * T_DIM + t0 + (l & 15) * 4, &gst[buf][(8 + w) * 260]);
        }
    };
    auto STAGE_W2 = [&](int tc) {
        gld16v(w2g + (size_t)tc * 4096 + w * 512 + l * 8, &w2s[w * 512]);
    };
    // transpose-convert xfst[buf] fp32 [f][t] -> xbt bf16 [t][f]; 320 threads
    auto CONVERT = [&](int buf) {
        if (tid < 320) {
            int g = tid >> 5, tp = tid & 31;      // g = f-quad 0..9, tp = t-pair
            const float* src = &xfst[buf][g * 260 + 2 * tp];
            float a0 = src[0],   b0 = src[1];
            float a1 = src[64],  b1 = src[65];
            float a2 = src[128], b2 = src[129];
            float a3 = src[192], b3 = src[193];
            uint2v lo, hi;
            lo.x = (unsigned int)f2bf(a0) | ((unsigned int)f2bf(a1) << 16);
            lo.y = (unsigned int)f2bf(a2) | ((unsigned int)f2bf(a3) << 16);
            hi.x = (unsigned int)f2bf(b0) | ((unsigned int)f2bf(b1) << 16);
            hi.y = (unsigned int)f2bf(b2) | ((unsigned int)f2bf(b3) << 16);
            int t = 2 * tp;
            *(uint2v*)&xbt[t * 72 + g * 4] = lo;
            *(uint2v*)&xbt[(t + 1) * 72 + g * 4] = hi;
        }
    };

    // zero the f>=40 region of xbt once (stays zero; W1 pad rows are zero too)
    {
        int t = tid >> 3, k = tid & 7;
        *(uint2v*)&xbt[t * 72 + 40 + k * 4] = (uint2v){0u, 0u};   // covers f 40..71
    }
    STAGE_XG(0, 0);
    __syncthreads();
    for (int tc = 0; tc < 16; tc++) {
        int cur = tc & 1;
        CONVERT(cur);
        STAGE_W2(tc);
        __syncthreads();                       // A: xbt + w2s ready (vmcnt drained)
        if (tc < 15) STAGE_XG(cur ^ 1, tc + 1);  // prefetch overlaps compute
        // X_bar^T via MFMA: D[t][o], lane holds t = ni*16 + q*4+j at fixed o = og
        f32x4 acc1[4] = {};
        #pragma unroll
        for (int ni = 0; ni < 4; ni++)
            #pragma unroll
            for (int ks = 0; ks < 2; ks++) {
                bf16x8 bx = *(const bf16x8*)&xbt[(ni * 16 + rr) * 72 + ks * 32 + q * 8];
                acc1[ni] = __builtin_amdgcn_mfma_f32_16x16x32_bf16(bx, aw[ks], acc1[ni], 0, 0, 0);
            }
        // gate (fp32 LDS, lane-fixed row am) + pack -> one ds_write_b64 per ni
        const float* gr = &gst[cur][amg];
        #pragma unroll
        for (int ni = 0; ni < 4; ni++) {
            f32x4 gv = *(const f32x4*)(gr + ni * 16 + q * 4);
            float e0 = acc1[ni][0] * (lam * gv.x + oml);
            float e1 = acc1[ni][1] * (lam * gv.y + oml);
            float e2 = acc1[ni][2] * (lam * gv.z + oml);
            float e3 = acc1[ni][3] * (lam * gv.w + oml);
            uint2 pk;
            pk.x = (unsigned int)f2bf(e0) | ((unsigned int)f2bf(e1) << 16);
            pk.y = (unsigned int)f2bf(e2) | ((unsigned int)f2bf(e3) << 16);
            *(uint2*)&xtl[og * 72 + ni * 16 + q * 4] = pk;
        }
        // GEMM2: a2 row = og (same-wave RAW on xtl), b2 from swizzled w2s LDS
        #pragma unroll
        for (int ks2 = 0; ks2 < 2; ks2++) {
            bf16x8 a2 = *(const bf16x8*)&xtl[og * 72 + ks2 * 32 + q * 8];
            #pragma unroll
            for (int ni = 0; ni < 4; ni++) {
                int s = ni * 16 + rr;
                bf16x8 b2 = *(const bf16x8*)&w2s[s * 64 + (((ks2 * 4 + q) ^ (s & 7)) << 3)];
                acc2[ni] = __builtin_amdgcn_mfma_f32_16x16x32_bf16(a2, b2, acc2[ni], 0, 0, 0);
            }
        }
        __syncthreads();                       // B: drains prefetch; protects buffers
    }
    #pragma unroll
    for (int ni = 0; ni < 4; ni++)
        #pragma unroll
        for (int j = 0; j < 4; j++) {
            int row = w * 16 + q * 4 + j;
            if (row < D1_OUT) {
                int col = ni * 16 + rr;
                float v = acc2[ni][j] + Bias[row * D2_OUT + col];
                out[((size_t)b * D1_OUT + row) * D2_OUT + col] = fmaxf(v, 0.f);
            }
        }
}

extern "C" void kernel_launch(void* const* d_in, const int* in_sizes, int n_in,
                              void* d_out, int out_size, void* d_ws, size_t ws_size,
                              hipStream_t stream) {
    const float* x    = (const float*)d_in[0];
    const float* W1   = (const float*)d_in[1];
    const float* W    = (const float*)d_in[2];
    const float* W2   = (const float*)d_in[3];
    const float* Bias = (const float*)d_in[4];
    const float* lam  = (const float*)d_in[5];
    float* out = (float*)d_out;
    float* A   = out + OUT0_SZ;                    // second output region

    char* ws = (char*)d_ws;
    unsigned short* wfrag = (unsigned short*)(ws);              // 2 MB
    unsigned short* w2g   = (unsigned short*)(ws + 2097152);    // 128 KB
    unsigned short* w1p   = (unsigned short*)(ws + 2228224);    // 16 KB (total ~2.25 MB)

    hipLaunchKernelGGL(k_prep_small, dim3(73), dim3(256), 0, stream, W1, W, W2, w2g, w1p);
    hipLaunchKernelGGL(k_wfrag, dim3(256), dim3(256), 0, stream, W, wfrag);
    hipLaunchKernelGGL(k_gemm1sm, dim3(1280), dim3(512), 0, stream, x, wfrag, A);
    hipLaunchKernelGGL(k_fused, dim3(512), dim3(512), 0, stream, x, A, w1p, w2g, Bias, lam, out);
}